// Round 3
// baseline (1108.400 us; speedup 1.0000x reference)
//
#include <hip/hip_runtime.h>

typedef __bf16 bf16_t;
typedef bf16_t bf16x8 __attribute__((ext_vector_type(8)));
typedef bf16_t bf16x4 __attribute__((ext_vector_type(4)));
typedef float  f32x4  __attribute__((ext_vector_type(4)));

#define DEVFN __device__ __forceinline__

constexpr int BATCH = 256;
constexpr int DDIM  = 512;
constexpr int HDIM  = 2048;
constexpr int MNODE = 64;
constexpr int NC    = 32;
constexpr int NITER = 12;
constexpr int PT    = 10;
constexpr int ROWS  = BATCH * MNODE;  // 16384

DEVFN float fast_tanh(float x) {
  float e = __builtin_amdgcn_exp2f(x * 2.8853900817779268f);
  return 1.0f - 2.0f * __builtin_amdgcn_rcpf(e + 1.0f);
}

DEVFN void gload_lds16(const void* g, void* l) {
  __builtin_amdgcn_global_load_lds(
      (__attribute__((address_space(1))) void*)(g),
      (__attribute__((address_space(3))) void*)(l), 16, 0, 0);
}

DEVFN f32x4 mfma16(bf16x8 a, bf16x8 b, f32x4 c) {
  return __builtin_amdgcn_mfma_f32_16x16x32_bf16(a, b, c, 0, 0, 0);
}

// One 8KB staging round (512 threads x 16B = 64 rows of 128B) with the XOR
// swizzle baked into the GLOBAL source address; LDS dest stays linear.
DEVFN void stage_round(const bf16_t* g, int ldK, char* buf, int tid, int j) {
  const int t = j * 512 + tid;
  const int row = t >> 3;
  const int k = ((tid & 7) ^ (row & 7)) * 8;
  gload_lds16(g + (size_t)row * ldK + k, buf + t * 16);
}

// Swizzled bf16x8 fragment read: rows of 64 bf16 (128B), 16B slot s of row r
// holds global slot s ^ (r&7).
DEVFN bf16x8 frag(const void* buf, int row, int ks, int lg) {
  const int byte = row * 128 + ((ks * 64 + lg * 16) ^ ((row & 7) << 4));
  return *(const bf16x8*)((const char*)buf + byte);
}

// ---------------------------------------------------------------------------
// Prep: Kmat[64][64], Tmat[16 used of 64][64] (bf16 row-major).
// X_next = Kmat @ F_b + y0 ; traj_p = Tmat @ F_b + y0.
// ---------------------------------------------------------------------------
__global__ __launch_bounds__(256) void prep_matrices(
    const float* __restrict__ tspan, bf16_t* __restrict__ Kmat,
    bf16_t* __restrict__ Tmat) {
  __shared__ float sphi[NC][MNODE];
  __shared__ float spsi[NC][MNODE];
  __shared__ float sA32[NC][NC];
  __shared__ float sAP[NC][MNODE];
  __shared__ float sphis[NC][PT];

  const int tid = threadIdx.x;
  const float t0 = tspan[0], t1 = tspan[PT - 1];
  const float half = 0.5f * (t1 - t0);
  const float pi = 3.14159265358979323846f;

  for (int i = tid; i < NC * MNODE; i += 256) {
    int n = i >> 6, m = i & 63;
    float th = pi * (float)m / 63.0f;
    float ph = cosf((float)n * th);
    sphi[n][m] = ph;
    float w = (m == 0 || m == 63) ? 0.5f : 1.0f;
    spsi[n][m] = ph * w * (2.0f / 63.0f) * (n == 0 ? 0.5f : 1.0f);
  }
  for (int i = tid; i < NC * NC; i += 256) {
    int j = i >> 5, q = i & 31;
    float v = 0.f;
    for (int k = 1; k < NC; ++k) {
      float dk = half / (2.0f * (float)k);
      float dval = 0.f;
      if (q == k - 1) dval += dk;
      if (q == k + 1) dval -= dk;
      float pj = (j == 0) ? ((k & 1) ? 1.0f : -1.0f) : ((j == k) ? 1.0f : 0.0f);
      v += pj * dval;
    }
    sA32[j][q] = v;
  }
  for (int i = tid; i < NC * PT; i += 256) {
    int n = i / PT, p = i % PT;
    float tau = -1.0f + 2.0f * (tspan[p] - t0) / (t1 - t0);
    tau = fminf(1.0f, fmaxf(-1.0f, tau));
    sphis[n][p] = cosf((float)n * acosf(tau));
  }
  __syncthreads();
  for (int i = tid; i < NC * MNODE; i += 256) {
    int n = i >> 6, m = i & 63;
    float v = 0.f;
    for (int q = 0; q < NC; ++q) v += sA32[n][q] * spsi[q][m];
    sAP[n][m] = v;
  }
  __syncthreads();
  for (int i = tid; i < MNODE * MNODE; i += 256) {
    int m = i >> 6, mp = i & 63;
    float v = 0.f;
    for (int n = 0; n < NC; ++n) v += sphi[n][m] * sAP[n][mp];
    Kmat[i] = (bf16_t)v;
  }
  for (int i = tid; i < 16 * MNODE; i += 256) {
    int p = i >> 6, mp = i & 63;
    float v = 0.f;
    if (p < PT) {
      for (int n = 0; n < NC; ++n) v += sphis[n][p] * sAP[n][mp];
    }
    Tmat[i] = (bf16_t)v;
  }
}

__global__ void transpose_bf16(const float* __restrict__ src,
                               bf16_t* __restrict__ dst, int R, int C) {
  __shared__ float tile[32][33];
  const int bx = blockIdx.x * 32, by = blockIdx.y * 32;
  const int tx = threadIdx.x, ty = threadIdx.y;
#pragma unroll
  for (int i = 0; i < 32; i += 8)
    tile[ty + i][tx] = src[(size_t)(by + ty + i) * C + (bx + tx)];
  __syncthreads();
#pragma unroll
  for (int i = 0; i < 32; i += 8)
    dst[(size_t)(bx + ty + i) * R + (by + tx)] = (bf16_t)tile[tx][ty + i];
}

__global__ void init_X(const float* __restrict__ y0, bf16_t* __restrict__ X) {
  size_t i = (size_t)blockIdx.x * 256 + threadIdx.x;
  int d = (int)(i & 511);
  int row = (int)(i >> 9);
  int b = row >> 6;
  X[i] = (bf16_t)y0[((size_t)b << 9) + d];
}

// ---------------------------------------------------------------------------
// Fused MFMA GEMM, T3+T4+T5 schedule.
// BM=256, BN=128, BK=64, 512 threads (8 waves, 4M x 2N -> 64x64 per wave).
// Triple-buffered LDS K-tiles (3 x 48KB); per K-tile 2 phases, each:
//   {ds_read frags | 3 stage rounds of tile t+2} -> s_barrier -> lgkmcnt(0)
//   -> setprio(1) + 16 MFMA + setprio(0) -> [vmcnt(6) at tile end] -> barrier
// vmcnt never drains to 0 in steady state (loads span 2 tiles of compute).
// FUSE=0: C = act(A @ Bt^T + bias)           (row-major bf16)
// FUSE=1: F = A@Bt^T+bias; X = Kmat@F + y0   (4 batches/tile)
// FUSE=2: F = A@Bt^T+bias; out = Tmat@F + y0 (f32 traj rows p<10)
// ---------------------------------------------------------------------------
template <int TANH, int FUSE, int NXB, int KDIM>
__global__ __launch_bounds__(512, 2) void gemm_k(
    const bf16_t* __restrict__ A, const bf16_t* __restrict__ Bt,
    const float* __restrict__ bias, const bf16_t* __restrict__ KT,
    const float* __restrict__ y0, bf16_t* __restrict__ Cb,
    float* __restrict__ Cf) {
  constexpr int NC2 = NXB * 128;
  constexpr int nk = KDIM / 64;
  // 3 slots x (A 32KB + B 16KB) = 144KB, + 8KB KT for fused variants
  __shared__ alignas(16) char lds[FUSE ? 155648 : 147456];
  char* KTs = lds + 147456;

  const int tid = threadIdx.x;
  const int wid = tid >> 6, lane = tid & 63;
  const int lr = lane & 15, lg = lane >> 4;
  const int nwg = gridDim.x;
  const int id = blockIdx.x;
  const int swz = (id & 7) * (nwg >> 3) + (id >> 3);  // XCD-contiguous chunks
  const int bx = swz % NXB, by = swz / NXB;
  const int row0 = by * 256, col0 = bx * 128;
  const int wr = (wid >> 1) * 64, wc = (wid & 1) * 64;

  const bf16_t* Ag = A + (size_t)row0 * KDIM;
  const bf16_t* Bg = Bt + (size_t)col0 * KDIM;

  // ---- prologue: KT (oldest), then K-tiles 0 and 1 ----
  if constexpr (FUSE > 0) stage_round(KT, 64, KTs, tid, 0);
#pragma unroll
  for (int j = 0; j < 4; ++j) stage_round(Ag, KDIM, lds, tid, j);
#pragma unroll
  for (int j = 0; j < 2; ++j) stage_round(Bg, KDIM, lds + 32768, tid, j);
#pragma unroll
  for (int j = 0; j < 4; ++j) stage_round(Ag + 64, KDIM, lds + 49152, tid, j);
#pragma unroll
  for (int j = 0; j < 2; ++j)
    stage_round(Bg + 64, KDIM, lds + 49152 + 32768, tid, j);
  asm volatile("s_waitcnt vmcnt(6)" ::: "memory");  // tile 0 (+KT) landed
  __builtin_amdgcn_s_barrier();

  const f32x4 fz = {0.f, 0.f, 0.f, 0.f};
  f32x4 acc[4][4];
#pragma unroll
  for (int i = 0; i < 4; ++i)
#pragma unroll
    for (int j = 0; j < 4; ++j) acc[i][j] = fz;

  for (int t = 0; t < nk; ++t) {
    const int slot = t % 3;
    const char* Ab = lds + slot * 49152;
    const char* Bb = Ab + 32768;
    const bool pf = (t + 2 < nk);
    const int slot2 = (t + 2) % 3;
    char* A2 = lds + slot2 * 49152;
    char* B2 = A2 + 32768;
    const bf16_t* gA2 = Ag + (size_t)(t + 2) * 64;
    const bf16_t* gB2 = Bg + (size_t)(t + 2) * 64;

    bf16x8 bfv[4][2], af[2][2];
    // ---------- phase 0: B-frags (held both phases) + A m0,m1 ----------
#pragma unroll
    for (int ni = 0; ni < 4; ++ni)
#pragma unroll
      for (int ks = 0; ks < 2; ++ks)
        bfv[ni][ks] = frag(Bb, wc + ni * 16 + lr, ks, lg);
#pragma unroll
    for (int mi = 0; mi < 2; ++mi)
#pragma unroll
      for (int ks = 0; ks < 2; ++ks)
        af[mi][ks] = frag(Ab, wr + mi * 16 + lr, ks, lg);
    if (pf) {
      stage_round(gA2, KDIM, A2, tid, 0);
      stage_round(gA2, KDIM, A2, tid, 1);
      stage_round(gB2, KDIM, B2, tid, 0);
    }
    __builtin_amdgcn_s_barrier();
    asm volatile("s_waitcnt lgkmcnt(0)" ::: "memory");
    __builtin_amdgcn_sched_barrier(0);
    __builtin_amdgcn_s_setprio(1);
#pragma unroll
    for (int mi = 0; mi < 2; ++mi)
#pragma unroll
      for (int ni = 0; ni < 4; ++ni)
#pragma unroll
        for (int ks = 0; ks < 2; ++ks)
          acc[mi][ni] = mfma16(af[mi][ks], bfv[ni][ks], acc[mi][ni]);
    __builtin_amdgcn_s_setprio(0);
    __builtin_amdgcn_sched_barrier(0);
    __builtin_amdgcn_s_barrier();

    // ---------- phase 1: A m2,m3 ----------
#pragma unroll
    for (int mi = 0; mi < 2; ++mi)
#pragma unroll
      for (int ks = 0; ks < 2; ++ks)
        af[mi][ks] = frag(Ab, wr + (mi + 2) * 16 + lr, ks, lg);
    if (pf) {
      stage_round(gA2, KDIM, A2, tid, 2);
      stage_round(gA2, KDIM, A2, tid, 3);
      stage_round(gB2, KDIM, B2, tid, 1);
    }
    __builtin_amdgcn_s_barrier();
    asm volatile("s_waitcnt lgkmcnt(0)" ::: "memory");
    __builtin_amdgcn_sched_barrier(0);
    __builtin_amdgcn_s_setprio(1);
#pragma unroll
    for (int mi = 0; mi < 2; ++mi)
#pragma unroll
      for (int ni = 0; ni < 4; ++ni)
#pragma unroll
        for (int ks = 0; ks < 2; ++ks)
          acc[mi + 2][ni] = mfma16(af[mi][ks], bfv[ni][ks], acc[mi + 2][ni]);
    __builtin_amdgcn_s_setprio(0);
    __builtin_amdgcn_sched_barrier(0);
    // wait for tile t+1's staging (never 0 in steady state)
    if (t < nk - 2) {
      asm volatile("s_waitcnt vmcnt(6)" ::: "memory");
    } else if (t == nk - 2) {
      asm volatile("s_waitcnt vmcnt(0)" ::: "memory");
    }
    __builtin_amdgcn_s_barrier();
  }

  if constexpr (FUSE == 0) {
#pragma unroll
    for (int ni = 0; ni < 4; ++ni) {
      const int col = col0 + wc + ni * 16 + lr;
      const float bv = bias[col];
#pragma unroll
      for (int mi = 0; mi < 4; ++mi) {
        const int row = row0 + wr + mi * 16 + lg * 4;
#pragma unroll
        for (int r = 0; r < 4; ++r) {
          float v = acc[mi][ni][r] + bv;
          if constexpr (TANH) v = fast_tanh(v);
          Cb[(size_t)(row + r) * NC2 + col] = (bf16_t)v;
        }
      }
    }
  } else {
    // F -> LDS transposed: [batch_loc(4)][d_local(128)][m(64)], swizzled rows
    char* Fs = lds;
#pragma unroll
    for (int ni = 0; ni < 4; ++ni) {
      const int col = col0 + wc + ni * 16 + lr;
      const float bv = bias[col];
      const int fr = (wr >> 6) * 128 + wc + ni * 16 + lr;
#pragma unroll
      for (int mi = 0; mi < 4; ++mi) {
        const int m0 = mi * 16 + lg * 4;
        bf16x4 pack;
#pragma unroll
        for (int r = 0; r < 4; ++r) pack[r] = (bf16_t)(acc[mi][ni][r] + bv);
        *(bf16x4*)(Fs + fr * 128 + ((m0 * 2) ^ ((fr & 7) << 4))) = pack;
      }
    }
    __syncthreads();

    const int bb = wid >> 1;         // batch within tile (wave's row block)
    const int dh = (wid & 1) * 64;   // d-half (== wc)
    constexpr int MI2 = (FUSE == 1) ? 4 : 1;
    f32x4 acc2[MI2][4];
#pragma unroll
    for (int mi = 0; mi < MI2; ++mi)
#pragma unroll
      for (int ni = 0; ni < 4; ++ni) acc2[mi][ni] = fz;
#pragma unroll
    for (int ks = 0; ks < 2; ++ks) {
      bf16x8 bf2[4];
#pragma unroll
      for (int ni = 0; ni < 4; ++ni)
        bf2[ni] = frag(Fs, bb * 128 + dh + ni * 16 + lr, ks, lg);
#pragma unroll
      for (int mi = 0; mi < MI2; ++mi) {
        bf16x8 afk = frag(KTs, mi * 16 + lr, ks, lg);
#pragma unroll
        for (int ni = 0; ni < 4; ++ni)
          acc2[mi][ni] = mfma16(afk, bf2[ni], acc2[mi][ni]);
      }
    }
    const int b = (row0 >> 6) + bb;
#pragma unroll
    for (int ni = 0; ni < 4; ++ni) {
      const int dg = col0 + dh + ni * 16 + lr;
      const float yv = y0[(size_t)b * DDIM + dg];
      if constexpr (FUSE == 1) {
#pragma unroll
        for (int mi = 0; mi < 4; ++mi)
#pragma unroll
          for (int r = 0; r < 4; ++r) {
            const int m = mi * 16 + lg * 4 + r;
            Cb[((size_t)b * 64 + m) * DDIM + dg] =
                (bf16_t)(acc2[mi][ni][r] + yv);
          }
      } else {
#pragma unroll
        for (int r = 0; r < 4; ++r) {
          const int p = lg * 4 + r;
          if (p < PT)
            Cf[(size_t)p * BATCH * DDIM + (size_t)b * DDIM + dg] =
                acc2[0][ni][r] + yv;
        }
      }
    }
  }
}

// ---------------------------------------------------------------------------
extern "C" void kernel_launch(void* const* d_in, const int* in_sizes, int n_in,
                              void* d_out, int out_size, void* d_ws,
                              size_t ws_size, hipStream_t stream) {
  (void)in_sizes; (void)n_in; (void)out_size;
  const float* y0 = (const float*)d_in[0];
  const float* tspan = (const float*)d_in[1];
  const float* W1 = (const float*)d_in[2];
  const float* b1 = (const float*)d_in[3];
  const float* W2 = (const float*)d_in[4];
  const float* b2 = (const float*)d_in[5];
  float* out = (float*)d_out;

  char* ws = (char*)d_ws;
  const size_t szW1t = (size_t)HDIM * DDIM * 2;
  const size_t szW2t = (size_t)DDIM * HDIM * 2;
  const size_t szK = 64 * 64 * 2;
  const size_t szT = 64 * 64 * 2;  // 16 used rows, padded to 64 for staging
  const size_t szX = (size_t)ROWS * DDIM * 2;
  const size_t szH = (size_t)ROWS * HDIM * 2;
  if (ws_size < szW1t + szW2t + szK + szT + szX + szH) return;

  bf16_t* W1t = (bf16_t*)ws; ws += szW1t;
  bf16_t* W2t = (bf16_t*)ws; ws += szW2t;
  bf16_t* Kmat = (bf16_t*)ws; ws += szK;
  bf16_t* Tmat = (bf16_t*)ws; ws += szT;
  bf16_t* X = (bf16_t*)ws; ws += szX;
  bf16_t* H = (bf16_t*)ws; ws += szH;

  prep_matrices<<<1, 256, 0, stream>>>(tspan, Kmat, Tmat);
  transpose_bf16<<<dim3(HDIM / 32, DDIM / 32), dim3(32, 8), 0, stream>>>(
      W1, W1t, DDIM, HDIM);
  transpose_bf16<<<dim3(DDIM / 32, HDIM / 32), dim3(32, 8), 0, stream>>>(
      W2, W2t, HDIM, DDIM);
  init_X<<<(ROWS * DDIM) / 256, 256, 0, stream>>>(y0, X);

  for (int it = 0; it < NITER; ++it) {
    gemm_k<1, 0, 16, 512><<<1024, 512, 0, stream>>>(
        X, W1t, b1, nullptr, nullptr, H, nullptr);
    if (it < NITER - 1)
      gemm_k<0, 1, 4, 2048><<<256, 512, 0, stream>>>(
          H, W2t, b2, Kmat, y0, X, nullptr);
    else
      gemm_k<0, 2, 4, 2048><<<256, 512, 0, stream>>>(
          H, W2t, b2, Tmat, y0, nullptr, out);
  }
}

// Round 4
// 797.403 us; speedup vs baseline: 1.3900x; 1.3900x over previous
//
#include <hip/hip_runtime.h>

typedef __bf16 bf16_t;
typedef bf16_t bf16x8 __attribute__((ext_vector_type(8)));
typedef bf16_t bf16x4 __attribute__((ext_vector_type(4)));
typedef float  f32x4  __attribute__((ext_vector_type(4)));

#define DEVFN __device__ __forceinline__

constexpr int BATCH = 256;
constexpr int DDIM  = 512;
constexpr int HDIM  = 2048;
constexpr int MNODE = 64;
constexpr int NC    = 32;
constexpr int NITER = 12;
constexpr int PT    = 10;
constexpr int CROWS = BATCH * NC;  // 8192 coefficient rows

DEVFN float fast_tanh(float x) {
  float e = __builtin_amdgcn_exp2f(x * 2.8853900817779268f);
  return 1.0f - 2.0f * __builtin_amdgcn_rcpf(e + 1.0f);
}

DEVFN void gload_lds16(const void* g, void* l) {
  __builtin_amdgcn_global_load_lds(
      (__attribute__((address_space(1))) void*)(g),
      (__attribute__((address_space(3))) void*)(l), 16, 0, 0);
}

DEVFN f32x4 mfma16(bf16x8 a, bf16x8 b, f32x4 c) {
  return __builtin_amdgcn_mfma_f32_16x16x32_bf16(a, b, c, 0, 0, 0);
}

// 4KB staging round, 256 threads x 16B; rows of 64 bf16 (128B); XOR swizzle
// baked into the GLOBAL source address (LDS dest linear, per global_load_lds).
DEVFN void stage256(const bf16_t* g, int ldK, char* buf, int tid, int j) {
  const int t = j * 256 + tid;
  const int row = t >> 3;
  const int k = ((tid & 7) ^ (row & 7)) * 8;
  gload_lds16(g + (size_t)row * ldK + k, buf + t * 16);
}

// Swizzled bf16x8 fragment read: rows of 64 bf16 (128B); 16B slot s of row r
// holds global slot s ^ (r&7).
DEVFN bf16x8 frag(const void* buf, int row, int ks, int lg) {
  const int byte = row * 128 + ((ks * 64 + lg * 16) ^ ((row & 7) << 4));
  return *(const bf16x8*)((const char*)buf + byte);
}

// ---------------------------------------------------------------------------
// Prep: PhiT[64m][32n] (bf16), M2[32n'][64m] = A32@psi (bf16),
// PS[16p][32n] (f32, zero for p>=10), a2s[32] = rowsum(M2) (f32).
// ---------------------------------------------------------------------------
__global__ __launch_bounds__(256) void prep_matrices(
    const float* __restrict__ tspan, bf16_t* __restrict__ PhiT,
    bf16_t* __restrict__ M2, float* __restrict__ PS,
    float* __restrict__ a2s) {
  __shared__ float sphi[NC][MNODE];
  __shared__ float spsi[NC][MNODE];
  __shared__ float sA32[NC][NC];
  __shared__ float sAP[NC][MNODE];
  __shared__ float sphis[NC][PT];

  const int tid = threadIdx.x;
  const float t0 = tspan[0], t1 = tspan[PT - 1];
  const float half = 0.5f * (t1 - t0);
  const float pi = 3.14159265358979323846f;

  for (int i = tid; i < NC * MNODE; i += 256) {
    int n = i >> 6, m = i & 63;
    float th = pi * (float)m / 63.0f;
    float ph = cosf((float)n * th);
    sphi[n][m] = ph;
    float w = (m == 0 || m == 63) ? 0.5f : 1.0f;
    spsi[n][m] = ph * w * (2.0f / 63.0f) * (n == 0 ? 0.5f : 1.0f);
  }
  for (int i = tid; i < NC * NC; i += 256) {
    int j = i >> 5, q = i & 31;
    float v = 0.f;
    for (int k = 1; k < NC; ++k) {
      float dk = half / (2.0f * (float)k);
      float dval = 0.f;
      if (q == k - 1) dval += dk;
      if (q == k + 1) dval -= dk;
      float pj = (j == 0) ? ((k & 1) ? 1.0f : -1.0f) : ((j == k) ? 1.0f : 0.0f);
      v += pj * dval;
    }
    sA32[j][q] = v;
  }
  for (int i = tid; i < NC * PT; i += 256) {
    int n = i / PT, p = i % PT;
    float tau = -1.0f + 2.0f * (tspan[p] - t0) / (t1 - t0);
    tau = fminf(1.0f, fmaxf(-1.0f, tau));
    sphis[n][p] = cosf((float)n * acosf(tau));
  }
  __syncthreads();
  for (int i = tid; i < NC * MNODE; i += 256) {
    int n = i >> 6, m = i & 63;
    float v = 0.f;
    for (int q = 0; q < NC; ++q) v += sA32[n][q] * spsi[q][m];
    sAP[n][m] = v;
  }
  __syncthreads();
  for (int i = tid; i < MNODE * NC; i += 256) {  // PhiT[m][n]
    int m = i >> 5, n = i & 31;
    PhiT[i] = (bf16_t)sphi[n][m];
  }
  for (int i = tid; i < NC * MNODE; i += 256) {  // M2[n'][m]
    int n = i >> 6, m = i & 63;
    M2[i] = (bf16_t)sAP[n][m];
  }
  for (int i = tid; i < 16 * NC; i += 256) {     // PS[p][n]
    int p = i >> 5, n = i & 31;
    PS[i] = (p < PT) ? sphis[n][p] : 0.f;
  }
  if (tid < NC) {
    float s = 0.f;
    for (int m = 0; m < MNODE; ++m) s += sAP[tid][m];
    a2s[tid] = s;
  }
}

// Transpose f32 [R][C] -> bf16 [C][R]
__global__ void transpose_bf16(const float* __restrict__ src,
                               bf16_t* __restrict__ dst, int R, int C) {
  __shared__ float tile[32][33];
  const int bx = blockIdx.x * 32, by = blockIdx.y * 32;
  const int tx = threadIdx.x, ty = threadIdx.y;
#pragma unroll
  for (int i = 0; i < 32; i += 8)
    tile[ty + i][tx] = src[(size_t)(by + ty + i) * C + (bx + tx)];
  __syncthreads();
#pragma unroll
  for (int i = 0; i < 32; i += 8)
    dst[(size_t)(bx + ty + i) * R + (by + tx)] = (bf16_t)tile[tx][ty + i];
}

// Bc[b*32+n][d] = (n==0) ? y0[b][d] : 0
__global__ void init_Bc(const float* __restrict__ y0, bf16_t* __restrict__ Bc) {
  size_t i = (size_t)blockIdx.x * 256 + threadIdx.x;  // < CROWS*DDIM
  int d = (int)(i & 511);
  int row = (int)(i >> 9);
  int n = row & 31, b = row >> 5;
  Bc[i] = (n == 0) ? (bf16_t)y0[((size_t)b << 9) + d] : (bf16_t)0.f;
}

// ---------------------------------------------------------------------------
// Kernel A: G = Bc@W1^T tile [128 rows(4 batches x 32 coeffs) x 128 h], K=512.
// Epilogue (in-LDS, per batch): E^T = G^T@PhiT + b1; H = tanh(E);
// C2 = M2@H  -> global [CROWS x 2048] bf16.
// ---------------------------------------------------------------------------
__global__ __launch_bounds__(256, 2) void mlp_front(
    const bf16_t* __restrict__ Bc, const bf16_t* __restrict__ W1t,
    const float* __restrict__ b1, const bf16_t* __restrict__ PhiT,
    const bf16_t* __restrict__ M2, bf16_t* __restrict__ C2) {
  // [0,32K): A dbuf (2x16KB) | epilogue Gs [4 bloc][128 h][64B swz-n]
  // [32K,64K): B dbuf (2x16KB) | epilogue Hs [128 h][128B swz-m] (first 16KB)
  // [64K,+4K): PhiTs ; [+4K,+8K): M2s
  __shared__ alignas(16) char lds[73728];
  bf16_t* As = (bf16_t*)lds;
  bf16_t* Bs = (bf16_t*)(lds + 32768);
  char* Gs = lds;
  char* Hs = lds + 32768;
  const char* PhiTs = lds + 65536;
  const char* M2s = lds + 69632;

  const int tid = threadIdx.x;
  const int wid = tid >> 6, lane = tid & 63;
  const int lr = lane & 15, lg = lane >> 4;
  const int id = blockIdx.x, nwg = gridDim.x;
  const int swz = (id & 7) * (nwg >> 3) + (id >> 3);
  const int bx = swz & 15, by = swz >> 4;  // 16 col-blocks, 64 row-blocks
  const int row0 = by * 128, col0 = bx * 128;
  const int wr = (wid >> 1) * 64, wc = (wid & 1) * 64;

  const bf16_t* Ag = Bc + (size_t)row0 * DDIM;
  const bf16_t* Bg = W1t + (size_t)col0 * DDIM;

  // prologue: extras (oldest), then K-tile 0
  {
    int rowp = tid >> 2;
    int kp = ((tid & 3) ^ (rowp & 3)) * 8;  // 64B rows
    gload_lds16(PhiT + rowp * 32 + kp, lds + 65536 + tid * 16);
    int rowm = tid >> 3;
    int km = ((tid & 7) ^ (rowm & 7)) * 8;  // 128B rows
    gload_lds16(M2 + rowm * 64 + km, lds + 69632 + tid * 16);
  }
#pragma unroll
  for (int j = 0; j < 4; ++j) stage256(Ag, DDIM, (char*)As, tid, j);
#pragma unroll
  for (int j = 0; j < 4; ++j) stage256(Bg, DDIM, (char*)Bs, tid, j);

  const f32x4 fz = {0.f, 0.f, 0.f, 0.f};
  f32x4 acc[4][4];
#pragma unroll
  for (int i = 0; i < 4; ++i)
#pragma unroll
    for (int j = 0; j < 4; ++j) acc[i][j] = fz;

  constexpr int nk = DDIM / 64;  // 8
  for (int kt = 0; kt < nk; ++kt) {
    const int cur = kt & 1;
    if (kt + 1 < nk) {
#pragma unroll
      for (int j = 0; j < 4; ++j)
        stage256(Ag + (kt + 1) * 64, DDIM, (char*)(As + (cur ^ 1) * 8192), tid, j);
#pragma unroll
      for (int j = 0; j < 4; ++j)
        stage256(Bg + (kt + 1) * 64, DDIM, (char*)(Bs + (cur ^ 1) * 8192), tid, j);
      asm volatile("s_waitcnt vmcnt(8)" ::: "memory");
    } else {
      asm volatile("s_waitcnt vmcnt(0)" ::: "memory");
    }
    __builtin_amdgcn_s_barrier();
    __builtin_amdgcn_sched_barrier(0);
    const bf16_t* Ab = As + cur * 8192;
    const bf16_t* Bb = Bs + cur * 8192;
#pragma unroll
    for (int ks = 0; ks < 2; ++ks) {
      bf16x8 af[4], bfv[4];
#pragma unroll
      for (int mi = 0; mi < 4; ++mi) af[mi] = frag(Ab, wr + mi * 16 + lr, ks, lg);
#pragma unroll
      for (int ni = 0; ni < 4; ++ni) bfv[ni] = frag(Bb, wc + ni * 16 + lr, ks, lg);
#pragma unroll
      for (int mi = 0; mi < 4; ++mi)
#pragma unroll
        for (int ni = 0; ni < 4; ++ni)
          acc[mi][ni] = mfma16(af[mi], bfv[ni], acc[mi][ni]);
    }
    __builtin_amdgcn_sched_barrier(0);
    __builtin_amdgcn_s_barrier();
  }

  // ---- epilogue: G -> Gs (transposed per batch, swizzled) ----
#pragma unroll
  for (int ni = 0; ni < 4; ++ni) {
    const int h = wc + ni * 16 + lr;
#pragma unroll
    for (int mi = 0; mi < 4; ++mi) {
      const int rl = wr + mi * 16 + lg * 4;
      const int bloc = rl >> 5, n0 = rl & 31;
      bf16x4 pk;
#pragma unroll
      for (int r = 0; r < 4; ++r) pk[r] = (bf16_t)acc[mi][ni][r];
      *(bf16x4*)(Gs + bloc * 8192 + h * 64 + ((n0 * 2) ^ ((h & 3) << 4))) = pk;
    }
  }
  __syncthreads();

  // hoisted operand frags (batch-invariant)
  bf16x8 pb[4];
#pragma unroll
  for (int ni = 0; ni < 4; ++ni) {
    const int m = ni * 16 + lr;
    pb[ni] = *(const bf16x8*)(PhiTs + m * 64 + ((lg * 16) ^ ((m & 3) << 4)));
  }
  bf16x8 am[2][2];
#pragma unroll
  for (int mi = 0; mi < 2; ++mi)
#pragma unroll
    for (int ks = 0; ks < 2; ++ks) am[mi][ks] = frag(M2s, mi * 16 + lr, ks, lg);

  const float* b1g = b1 + col0;
  const int bg0 = row0 >> 5;  // first global batch of tile

  for (int b = 0; b < 4; ++b) {
    // E^T slice: wave wid -> h rows [wid*32, wid*32+32), K = 32 coeffs
    f32x4 e[2][4];
#pragma unroll
    for (int i = 0; i < 2; ++i)
#pragma unroll
      for (int j = 0; j < 4; ++j) e[i][j] = fz;
#pragma unroll
    for (int mi2 = 0; mi2 < 2; ++mi2) {
      const int h = wid * 32 + mi2 * 16 + lr;
      bf16x8 ga = *(const bf16x8*)(Gs + b * 8192 + h * 64 +
                                   ((lg * 16) ^ ((h & 3) << 4)));
#pragma unroll
      for (int ni = 0; ni < 4; ++ni) e[mi2][ni] = mfma16(ga, pb[ni], e[mi2][ni]);
    }
    // H = tanh(E + b1) -> Hs [h][m] swizzled
#pragma unroll
    for (int mi2 = 0; mi2 < 2; ++mi2)
#pragma unroll
      for (int ni = 0; ni < 4; ++ni)
#pragma unroll
        for (int r = 0; r < 4; ++r) {
          const int h = wid * 32 + mi2 * 16 + lg * 4 + r;
          const int m = ni * 16 + lr;
          float v = fast_tanh(e[mi2][ni][r] + b1g[h]);
          *(bf16_t*)(Hs + h * 128 + ((m * 2) ^ ((h & 7) << 4))) = (bf16_t)v;
        }
    __syncthreads();
    // C2 = M2 @ H : wave wid -> h cols [wid*32, +32), K = 64 nodes
    f32x4 c2a[2][2];
#pragma unroll
    for (int i = 0; i < 2; ++i)
#pragma unroll
      for (int j = 0; j < 2; ++j) c2a[i][j] = fz;
#pragma unroll
    for (int ks = 0; ks < 2; ++ks) {
      bf16x8 hb[2];
#pragma unroll
      for (int ni2 = 0; ni2 < 2; ++ni2)
        hb[ni2] = frag(Hs, wid * 32 + ni2 * 16 + lr, ks, lg);
#pragma unroll
      for (int mi3 = 0; mi3 < 2; ++mi3)
#pragma unroll
        for (int ni2 = 0; ni2 < 2; ++ni2)
          c2a[mi3][ni2] = mfma16(am[mi3][ks], hb[ni2], c2a[mi3][ni2]);
    }
#pragma unroll
    for (int mi3 = 0; mi3 < 2; ++mi3)
#pragma unroll
      for (int ni2 = 0; ni2 < 2; ++ni2) {
        const int hg = col0 + wid * 32 + ni2 * 16 + lr;
#pragma unroll
        for (int r = 0; r < 4; ++r) {
          const int np = mi3 * 16 + lg * 4 + r;
          C2[((size_t)(bg0 + b) * 32 + np) * (size_t)HDIM + hg] =
              (bf16_t)c2a[mi3][ni2][r];
        }
      }
    __syncthreads();  // Hs reused next batch
  }
}

// ---------------------------------------------------------------------------
// Kernel B: Bc' = C2@W2^T + a2s[n]*b2[d] + (n==0)*y0[b][d].
// Tile 128 rows x 64 d, K=2048; grid 64x8=512 -> 2 blocks/CU.
// ---------------------------------------------------------------------------
__global__ __launch_bounds__(256, 2) void coef_back(
    const bf16_t* __restrict__ C2, const bf16_t* __restrict__ W2t,
    const float* __restrict__ b2, const float* __restrict__ a2s,
    const float* __restrict__ y0, bf16_t* __restrict__ Bc) {
  __shared__ alignas(16) char lds[49152];  // A dbuf 32KB + B dbuf 16KB
  bf16_t* As = (bf16_t*)lds;
  bf16_t* Bs = (bf16_t*)(lds + 32768);

  const int tid = threadIdx.x;
  const int wid = tid >> 6, lane = tid & 63;
  const int lr = lane & 15, lg = lane >> 4;
  const int id = blockIdx.x, nwg = gridDim.x;
  const int swz = (id & 7) * (nwg >> 3) + (id >> 3);
  const int bx = swz & 7, by = swz >> 3;  // 8 col-blocks, 64 row-blocks
  const int row0 = by * 128, col0 = bx * 64;
  const int wr = (wid >> 1) * 64, wc = (wid & 1) * 32;

  const bf16_t* Ag = C2 + (size_t)row0 * HDIM;
  const bf16_t* Bg = W2t + (size_t)col0 * HDIM;

#pragma unroll
  for (int j = 0; j < 4; ++j) stage256(Ag, HDIM, (char*)As, tid, j);
#pragma unroll
  for (int j = 0; j < 2; ++j) stage256(Bg, HDIM, (char*)Bs, tid, j);

  const f32x4 fz = {0.f, 0.f, 0.f, 0.f};
  f32x4 acc[4][2];
#pragma unroll
  for (int i = 0; i < 4; ++i) {
    acc[i][0] = fz;
    acc[i][1] = fz;
  }

  constexpr int nk = HDIM / 64;  // 32
  for (int kt = 0; kt < nk; ++kt) {
    const int cur = kt & 1;
    if (kt + 1 < nk) {
#pragma unroll
      for (int j = 0; j < 4; ++j)
        stage256(Ag + (kt + 1) * 64, HDIM, (char*)(As + (cur ^ 1) * 8192), tid, j);
#pragma unroll
      for (int j = 0; j < 2; ++j)
        stage256(Bg + (kt + 1) * 64, HDIM, (char*)(Bs + (cur ^ 1) * 4096), tid, j);
      asm volatile("s_waitcnt vmcnt(6)" ::: "memory");
    } else {
      asm volatile("s_waitcnt vmcnt(0)" ::: "memory");
    }
    __builtin_amdgcn_s_barrier();
    __builtin_amdgcn_sched_barrier(0);
    const bf16_t* Ab = As + cur * 8192;
    const bf16_t* Bb = Bs + cur * 4096;
#pragma unroll
    for (int ks = 0; ks < 2; ++ks) {
      bf16x8 af[4], bfv[2];
#pragma unroll
      for (int mi = 0; mi < 4; ++mi) af[mi] = frag(Ab, wr + mi * 16 + lr, ks, lg);
#pragma unroll
      for (int ni = 0; ni < 2; ++ni) bfv[ni] = frag(Bb, wc + ni * 16 + lr, ks, lg);
#pragma unroll
      for (int mi = 0; mi < 4; ++mi)
#pragma unroll
        for (int ni = 0; ni < 2; ++ni)
          acc[mi][ni] = mfma16(af[mi], bfv[ni], acc[mi][ni]);
    }
    __builtin_amdgcn_sched_barrier(0);
    __builtin_amdgcn_s_barrier();
  }

#pragma unroll
  for (int ni = 0; ni < 2; ++ni) {
    const int d = col0 + wc + ni * 16 + lr;
    const float b2v = b2[d];
#pragma unroll
    for (int mi = 0; mi < 4; ++mi) {
      const int rl = row0 + wr + mi * 16 + lg * 4;
#pragma unroll
      for (int r = 0; r < 4; ++r) {
        const int row = rl + r;
        const int np = row & 31, b = row >> 5;
        float v = acc[mi][ni][r] + a2s[np] * b2v;
        if (np == 0) v += y0[(size_t)b * DDIM + d];
        Bc[(size_t)row * DDIM + d] = (bf16_t)v;
      }
    }
  }
}

// traj[p,b,d] = sum_n PS[p][n] * Bc[b*32+n][d]
__global__ __launch_bounds__(256) void traj_eval(
    const bf16_t* __restrict__ Bc, const float* __restrict__ PS,
    float* __restrict__ out) {
  __shared__ bf16_t Bsh[NC * 128];
  const int b = blockIdx.x >> 2, d0 = (blockIdx.x & 3) * 128;
#pragma unroll
  for (int j = 0; j < 2; ++j) {
    const int t = j * 256 + threadIdx.x;
    const int n = t >> 4, dd = (t & 15) * 8;
    *(bf16x8*)(Bsh + n * 128 + dd) =
        *(const bf16x8*)(Bc + ((size_t)b * 32 + n) * DDIM + d0 + dd);
  }
  __syncthreads();
  for (int o = threadIdx.x; o < PT * 128; o += 256) {
    const int p = o >> 7, d = o & 127;
    float s = 0.f;
#pragma unroll
    for (int n = 0; n < NC; ++n) s += PS[p * 32 + n] * (float)Bsh[n * 128 + d];
    out[(size_t)p * BATCH * DDIM + (size_t)b * DDIM + d0 + d] = s;
  }
}

// ---------------------------------------------------------------------------
extern "C" void kernel_launch(void* const* d_in, const int* in_sizes, int n_in,
                              void* d_out, int out_size, void* d_ws,
                              size_t ws_size, hipStream_t stream) {
  (void)in_sizes; (void)n_in; (void)out_size;
  const float* y0 = (const float*)d_in[0];
  const float* tspan = (const float*)d_in[1];
  const float* W1 = (const float*)d_in[2];
  const float* b1 = (const float*)d_in[3];
  const float* W2 = (const float*)d_in[4];
  const float* b2 = (const float*)d_in[5];
  float* out = (float*)d_out;

  char* ws = (char*)d_ws;
  const size_t szW1t = (size_t)HDIM * DDIM * 2;
  const size_t szW2t = (size_t)DDIM * HDIM * 2;
  const size_t szPhiT = 64 * 32 * 2;
  const size_t szM2 = 32 * 64 * 2;
  const size_t szPS = 16 * 32 * 4;
  const size_t szA2s = 256;  // 32 f32, padded
  const size_t szBc = (size_t)CROWS * DDIM * 2;
  const size_t szC2 = (size_t)CROWS * HDIM * 2;
  if (ws_size < szW1t + szW2t + szPhiT + szM2 + szPS + szA2s + szBc + szC2)
    return;

  bf16_t* W1t = (bf16_t*)ws; ws += szW1t;
  bf16_t* W2t = (bf16_t*)ws; ws += szW2t;
  bf16_t* PhiT = (bf16_t*)ws; ws += szPhiT;
  bf16_t* M2 = (bf16_t*)ws; ws += szM2;
  float* PS = (float*)ws; ws += szPS;
  float* a2s = (float*)ws; ws += szA2s;
  bf16_t* Bc = (bf16_t*)ws; ws += szBc;
  bf16_t* C2 = (bf16_t*)ws; ws += szC2;

  prep_matrices<<<1, 256, 0, stream>>>(tspan, PhiT, M2, PS, a2s);
  transpose_bf16<<<dim3(HDIM / 32, DDIM / 32), dim3(32, 8), 0, stream>>>(
      W1, W1t, DDIM, HDIM);
  transpose_bf16<<<dim3(DDIM / 32, HDIM / 32), dim3(32, 8), 0, stream>>>(
      W2, W2t, HDIM, DDIM);
  init_Bc<<<(CROWS * DDIM) / 256, 256, 0, stream>>>(y0, Bc);

  for (int it = 0; it < NITER; ++it) {
    mlp_front<<<1024, 256, 0, stream>>>(Bc, W1t, b1, PhiT, M2, C2);
    coef_back<<<512, 256, 0, stream>>>(C2, W2t, b2, a2s, y0, Bc);
  }
  traj_eval<<<BATCH * 4, 256, 0, stream>>>(Bc, PS, out);
}